// Round 3
// baseline (165.225 us; speedup 1.0000x reference)
//
#include <hip/hip_runtime.h>

typedef __attribute__((ext_vector_type(8))) short short8;
typedef __attribute__((ext_vector_type(4))) float f32x4;
typedef unsigned int u32;
typedef unsigned short u16;

#define C_DIM 128
#define MT 7          // 112 rows = 7 m-tiles, all handled by every wave
#define XROWS 112
#define THREADS 256
#define WPK_PLANE 16384   // elems per plane: 8nt*4ks*64lane*8

// Packed MFMA B-fragments of W1/W2: [layer][half(hi,lo)][nt(8)][ks(4)][lane(64)][8] bf16.
__device__ __align__(16) u16 g_wpack[2][2][8][4][64][8];

__device__ __forceinline__ u16 bf16_rn(float x) {
    u32 u = __float_as_uint(x);
    u32 r = u + 0x7FFFu + ((u >> 16) & 1u);
    return (u16)(r >> 16);
}

__device__ __forceinline__ float silu_f(float x) {
    return x / (1.0f + __expf(-x));
}

__device__ __forceinline__ float dot4(float4 a, float4 b) {
    return a.x * b.x + a.y * b.y + a.z * b.z + a.w * b.w;
}

// rows of CG that matter: row 0 (iso), rows 4..8 (aniso m=0..4)
__constant__ float CG_TAB[6][9] = {
    {  0.5773502691896258f, 0.f, 0.f,  0.f, 0.5773502691896258f, 0.f,  0.f, 0.f, 0.5773502691896258f },
    {  0.f, 0.f, 0.7071067811865476f,  0.f, 0.f, 0.f,  0.7071067811865476f, 0.f, 0.f },
    {  0.f, 0.f, 0.f,  0.f, 0.f, 0.7071067811865476f,  0.f, 0.7071067811865476f, 0.f },
    { -0.4082482904638630f, 0.f, 0.f,  0.f, 0.8164965809277260f, 0.f,  0.f, 0.f, -0.4082482904638630f },
    {  0.f, 0.7071067811865476f, 0.f,  0.7071067811865476f, 0.f, 0.f,  0.f, 0.f, 0.f },
    { -0.7071067811865476f, 0.f, 0.f,  0.f, 0.f, 0.f,  0.f, 0.f, 0.7071067811865476f },
};

// one-shot: pack W1/W2 into MFMA B-fragment order, bf16 hi/lo planes
extern "C" __global__ void __launch_bounds__(512)
prep_wpack(const float* __restrict__ W1, const float* __restrict__ W2) {
    const int t = blockIdx.x * 512 + threadIdx.x;    // 0..4095
    const int layer = t >> 11;
    const int rem   = t & 2047;
    const int nt    = rem >> 8;
    const int ks    = (rem >> 6) & 3;
    const int lane  = rem & 63;
    const int j  = nt * 16 + (lane & 15);
    const int k0 = ks * 32 + (lane >> 4) * 8;
    const float* W = layer ? W2 : W1;
    const float* src = W + j * C_DIM + k0;
    short8 vh, vl;
    #pragma unroll
    for (int i = 0; i < 8; ++i) {
        const float v = src[i];
        const u16 h = bf16_rn(v);
        vh[i] = (short)h;
        vl[i] = (short)bf16_rn(v - __uint_as_float((u32)h << 16));
    }
    *(short8*)&g_wpack[layer][0][nt][ks][lane][0] = vh;
    *(short8*)&g_wpack[layer][1][nt][ks][lane][0] = vl;
}

// per-wave GEMM layer: X (single bf16 plane, LDS) x W (hi+lo planes, packed global).
// acc[mt][t] over all 7 m-tiles; wave owns n-tiles nt0, nt0+1.
// Next-ks B-fragments prefetched to hide L2 latency.
__device__ __forceinline__ void gemm_layer_pk(const u16* __restrict__ wpk,
                                              const u16* __restrict__ sX,
                                              int nt0, int l, f32x4 acc[MT][2]) {
    const int lr = l & 15;
    const u16* base0 = wpk + (((nt0    ) * 4) * 64 + l) * 8;
    const u16* base1 = wpk + (((nt0 + 1) * 4) * 64 + l) * 8;
    #pragma unroll
    for (int mt = 0; mt < MT; ++mt) {
        acc[mt][0] = (f32x4){0.f, 0.f, 0.f, 0.f};
        acc[mt][1] = (f32x4){0.f, 0.f, 0.f, 0.f};
    }
    short8 bh0 = *(const short8*)(base0);
    short8 bl0 = *(const short8*)(base0 + WPK_PLANE);
    short8 bh1 = *(const short8*)(base1);
    short8 bl1 = *(const short8*)(base1 + WPK_PLANE);
    #pragma unroll
    for (int ks = 0; ks < 4; ++ks) {
        short8 nh0, nl0, nh1, nl1;
        if (ks < 3) {
            const int o = (ks + 1) * 512;   // 512 elems per ks step
            nh0 = *(const short8*)(base0 + o);
            nl0 = *(const short8*)(base0 + WPK_PLANE + o);
            nh1 = *(const short8*)(base1 + o);
            nl1 = *(const short8*)(base1 + WPK_PLANE + o);
        }
        const int k0 = ks * 32 + (l >> 4) * 8;
        #pragma unroll
        for (int mt = 0; mt < MT; ++mt) {
            const int row = mt * 16 + lr;
            const int off = row * 128 + (k0 ^ ((row & 7) << 3));
            short8 ah = *(const short8*)(sX + off);
            acc[mt][0] = __builtin_amdgcn_mfma_f32_16x16x32_bf16(ah, bh0, acc[mt][0], 0, 0, 0);
            acc[mt][0] = __builtin_amdgcn_mfma_f32_16x16x32_bf16(ah, bl0, acc[mt][0], 0, 0, 0);
            acc[mt][1] = __builtin_amdgcn_mfma_f32_16x16x32_bf16(ah, bh1, acc[mt][1], 0, 0, 0);
            acc[mt][1] = __builtin_amdgcn_mfma_f32_16x16x32_bf16(ah, bl1, acc[mt][1], 0, 0, 0);
        }
        bh0 = nh0; bl0 = nl0; bh1 = nh1; bl1 = nl1;
    }
}

extern "C" __global__ void __launch_bounds__(THREADS, 4)
fused_stress(const float* __restrict__ emb,
             const float* __restrict__ b1,
             const float* __restrict__ b2,
             const float* __restrict__ W3, const float* __restrict__ b3,
             const float* __restrict__ wl2, const int* __restrict__ natoms,
             float* __restrict__ out, int NPG) {
    __shared__ u16 sX[XROWS * 128];     // 28 KB, single bf16 plane
    __shared__ float s_acc[6];          // [0]=iso sum, [1..5]=aniso sums

    const int tid = threadIdx.x;
    const int l   = tid & 63;
    const int w   = tid >> 6;           // wave 0..3
    const int lr  = l & 15;
    const int lkg = l >> 4;             // 0..3
    const int g   = blockIdx.x;
    const size_t nodebase = (size_t)g * (size_t)NPG;

    if (tid < 6) s_acc[tid] = 0.0f;
    __syncthreads();

    // ---- stage x0 rows -> sX (bf16, swizzled), zero-pad rows NPG..111 ----
    #pragma unroll 4
    for (int f = tid; f < XROWS * 32; f += THREADS) {
        const int row = f >> 5, c4 = f & 31;
        float4 v = make_float4(0.f, 0.f, 0.f, 0.f);
        if (row < NPG)
            v = *((const float4*)(emb + (nodebase + row) * 9 * C_DIM) + c4);
        const int ksw = (c4 * 4) ^ ((row & 7) << 3);
        u32 p01 = (u32)bf16_rn(v.x) | ((u32)bf16_rn(v.y) << 16);
        u32 p23 = (u32)bf16_rn(v.z) | ((u32)bf16_rn(v.w) << 16);
        *(uint2*)(&sX[row * 128 + ksw]) = make_uint2(p01, p23);
    }

    // ---- aniso stream: rows 4..8 of each node, dot w_l2, accumulate per m ----
    {
        const float4 wv = *((const float4*)wl2 + (l & 31));
        float a0 = 0.f, a1 = 0.f, a2 = 0.f, a3 = 0.f, a4 = 0.f;
        for (int node = w * 2 + (l >> 5); node < NPG; node += 8) {
            const float4* p = (const float4*)(emb + (nodebase + node) * 9 * C_DIM + 4 * C_DIM) + (l & 31);
            float4 v0 = p[0];
            float4 v1 = p[32];
            float4 v2 = p[64];
            float4 v3 = p[96];
            float4 v4 = p[128];
            a0 += dot4(v0, wv);
            a1 += dot4(v1, wv);
            a2 += dot4(v2, wv);
            a3 += dot4(v3, wv);
            a4 += dot4(v4, wv);
        }
        #pragma unroll
        for (int s = 1; s < 32; s <<= 1) {
            a0 += __shfl_xor(a0, s);
            a1 += __shfl_xor(a1, s);
            a2 += __shfl_xor(a2, s);
            a3 += __shfl_xor(a3, s);
            a4 += __shfl_xor(a4, s);
        }
        if ((l & 31) == 0) {
            atomicAdd(&s_acc[1], a0);
            atomicAdd(&s_acc[2], a1);
            atomicAdd(&s_acc[3], a2);
            atomicAdd(&s_acc[4], a3);
            atomicAdd(&s_acc[5], a4);
        }
    }
    __syncthreads();

    f32x4 acc[MT][2];
    const int nt0 = w * 2;

    // ---- layer 1: h = silu(x0 @ W1^T + b1) ----
    gemm_layer_pk(&g_wpack[0][0][0][0][0][0], sX, nt0, l, acc);
    __syncthreads();   // everyone done reading sX (x0)

    // write h back into sX (bf16, swizzled)
    {
        #pragma unroll
        for (int t = 0; t < 2; ++t) {
            const int j = (nt0 + t) * 16 + lr;
            const float bj = b1[j];
            #pragma unroll
            for (int mt = 0; mt < MT; ++mt) {
                #pragma unroll
                for (int r = 0; r < 4; ++r) {
                    const int row = mt * 16 + lkg * 4 + r;
                    const float hv = silu_f(acc[mt][t][r] + bj);
                    sX[row * 128 + (j ^ ((row & 7) << 3))] = bf16_rn(hv);
                }
            }
        }
    }
    __syncthreads();

    // ---- layer 2: h2 = silu(h @ W2^T + b2); s = h2 . W3 ; block-sum ----
    gemm_layer_pk(&g_wpack[1][0][0][0][0][0], sX, nt0, l, acc);
    {
        float w3j[2], b2j[2];
        #pragma unroll
        for (int t = 0; t < 2; ++t) {
            const int j = (nt0 + t) * 16 + lr;
            w3j[t] = W3[j];
            b2j[t] = b2[j];
        }
        float psum = 0.0f;
        #pragma unroll
        for (int mt = 0; mt < MT; ++mt) {
            #pragma unroll
            for (int r = 0; r < 4; ++r) {
                const int row = mt * 16 + lkg * 4 + r;
                if (row < NPG) {
                    psum += silu_f(acc[mt][0][r] + b2j[0]) * w3j[0]
                          + silu_f(acc[mt][1][r] + b2j[1]) * w3j[1];
                }
            }
        }
        // full-wave reduce (sums over lr and lkg; all lanes same graph)
        #pragma unroll
        for (int s = 1; s < 64; s <<= 1)
            psum += __shfl_xor(psum, s);
        if (l == 0)
            atomicAdd(&s_acc[0], psum);
    }
    __syncthreads();

    // ---- finalize: dec = [iso, 0,0,0, aniso]; out = dec @ CG ----
    if (tid < 9) {
        const float inv = 1.0f / (float)natoms[g];
        const float iso = (s_acc[0] + (float)NPG * b3[0]) * inv;
        float o = iso * CG_TAB[0][tid];
        #pragma unroll
        for (int m = 0; m < 5; ++m)
            o += (s_acc[1 + m] * inv) * CG_TAB[1 + m][tid];
        out[(size_t)g * 9 + tid] = o;
    }
}

extern "C" void kernel_launch(void* const* d_in, const int* in_sizes, int n_in,
                              void* d_out, int out_size, void* d_ws, size_t ws_size,
                              hipStream_t stream) {
    const float* emb    = (const float*)d_in[0];
    const float* W1     = (const float*)d_in[1];
    const float* b1     = (const float*)d_in[2];
    const float* W2     = (const float*)d_in[3];
    const float* b2     = (const float*)d_in[4];
    const float* W3     = (const float*)d_in[5];
    const float* b3     = (const float*)d_in[6];
    const float* wl2    = (const float*)d_in[7];
    const int*   natoms = (const int*)d_in[9];

    const int G   = in_sizes[9];
    const int N   = in_sizes[0] / (9 * C_DIM);
    const int NPG = N / G;   // 100 for this problem; kernel supports NPG <= 112

    prep_wpack<<<8, 512, 0, stream>>>(W1, W2);
    fused_stress<<<G, THREADS, 0, stream>>>(emb, b1, b2, W3, b3, wl2,
                                            natoms, (float*)d_out, NPG);
}

// Round 4
// 145.517 us; speedup vs baseline: 1.1354x; 1.1354x over previous
//
#include <hip/hip_runtime.h>

typedef __attribute__((ext_vector_type(8))) short short8;
typedef __attribute__((ext_vector_type(4))) float f32x4;
typedef unsigned int u32;
typedef unsigned short u16;

#define C_DIM 128
#define MT 7          // 112 rows = 7 m-tiles, all handled by every wave
#define XROWS 112
#define THREADS 256
#define WPK_PLANE 16384   // elems per plane: 8nt*4ks*64lane*8

// Packed MFMA B-fragments of W1/W2: [layer][half(hi,lo)][nt(8)][ks(4)][lane(64)][8] bf16.
__device__ __align__(16) u16 g_wpack[2][2][8][4][64][8];

__device__ __forceinline__ u16 bf16_rn(float x) {
    u32 u = __float_as_uint(x);
    u32 r = u + 0x7FFFu + ((u >> 16) & 1u);
    return (u16)(r >> 16);
}

__device__ __forceinline__ float silu_f(float x) {
    return x / (1.0f + __expf(-x));
}

__device__ __forceinline__ float dot4v(f32x4 a, f32x4 b) {
    return a[0] * b[0] + a[1] * b[1] + a[2] * b[2] + a[3] * b[3];
}

// rows of CG that matter: row 0 (iso), rows 4..8 (aniso m=0..4)
__constant__ float CG_TAB[6][9] = {
    {  0.5773502691896258f, 0.f, 0.f,  0.f, 0.5773502691896258f, 0.f,  0.f, 0.f, 0.5773502691896258f },
    {  0.f, 0.f, 0.7071067811865476f,  0.f, 0.f, 0.f,  0.7071067811865476f, 0.f, 0.f },
    {  0.f, 0.f, 0.f,  0.f, 0.f, 0.7071067811865476f,  0.f, 0.7071067811865476f, 0.f },
    { -0.4082482904638630f, 0.f, 0.f,  0.f, 0.8164965809277260f, 0.f,  0.f, 0.f, -0.4082482904638630f },
    {  0.f, 0.7071067811865476f, 0.f,  0.7071067811865476f, 0.f, 0.f,  0.f, 0.f, 0.f },
    { -0.7071067811865476f, 0.f, 0.f,  0.f, 0.f, 0.f,  0.f, 0.f, 0.7071067811865476f },
};

// one-shot: pack W1/W2 into MFMA B-fragment order, bf16 hi/lo planes
extern "C" __global__ void __launch_bounds__(512)
prep_wpack(const float* __restrict__ W1, const float* __restrict__ W2) {
    const int t = blockIdx.x * 512 + threadIdx.x;    // 0..4095
    const int layer = t >> 11;
    const int rem   = t & 2047;
    const int nt    = rem >> 8;
    const int ks    = (rem >> 6) & 3;
    const int lane  = rem & 63;
    const int j  = nt * 16 + (lane & 15);
    const int k0 = ks * 32 + (lane >> 4) * 8;
    const float* W = layer ? W2 : W1;
    const float* src = W + j * C_DIM + k0;
    short8 vh, vl;
    #pragma unroll
    for (int i = 0; i < 8; ++i) {
        const float v = src[i];
        const u16 h = bf16_rn(v);
        vh[i] = (short)h;
        vl[i] = (short)bf16_rn(v - __uint_as_float((u32)h << 16));
    }
    *(short8*)&g_wpack[layer][0][nt][ks][lane][0] = vh;
    *(short8*)&g_wpack[layer][1][nt][ks][lane][0] = vl;
}

// per-wave GEMM layer: X (single bf16 plane, LDS) x W (hi+lo planes, packed global).
// acc[mt][t] over all 7 m-tiles; wave owns n-tiles nt0, nt0+1.
// Next-ks B-fragments prefetched to hide L2 latency.
__device__ __forceinline__ void gemm_layer_pk(const u16* __restrict__ wpk,
                                              const u16* __restrict__ sX,
                                              int nt0, int l, f32x4 acc[MT][2]) {
    const int lr = l & 15;
    const u16* base0 = wpk + (((nt0    ) * 4) * 64 + l) * 8;
    const u16* base1 = wpk + (((nt0 + 1) * 4) * 64 + l) * 8;
    #pragma unroll
    for (int mt = 0; mt < MT; ++mt) {
        acc[mt][0] = (f32x4){0.f, 0.f, 0.f, 0.f};
        acc[mt][1] = (f32x4){0.f, 0.f, 0.f, 0.f};
    }
    short8 bh0 = *(const short8*)(base0);
    short8 bl0 = *(const short8*)(base0 + WPK_PLANE);
    short8 bh1 = *(const short8*)(base1);
    short8 bl1 = *(const short8*)(base1 + WPK_PLANE);
    #pragma unroll
    for (int ks = 0; ks < 4; ++ks) {
        short8 nh0, nl0, nh1, nl1;
        if (ks < 3) {
            const int o = (ks + 1) * 512;   // 512 elems per ks step
            nh0 = *(const short8*)(base0 + o);
            nl0 = *(const short8*)(base0 + WPK_PLANE + o);
            nh1 = *(const short8*)(base1 + o);
            nl1 = *(const short8*)(base1 + WPK_PLANE + o);
        }
        const int k0 = ks * 32 + (l >> 4) * 8;
        #pragma unroll
        for (int mt = 0; mt < MT; ++mt) {
            const int row = mt * 16 + lr;
            const int off = row * 128 + (k0 ^ ((row & 7) << 3));
            short8 ah = *(const short8*)(sX + off);
            acc[mt][0] = __builtin_amdgcn_mfma_f32_16x16x32_bf16(ah, bh0, acc[mt][0], 0, 0, 0);
            acc[mt][0] = __builtin_amdgcn_mfma_f32_16x16x32_bf16(ah, bl0, acc[mt][0], 0, 0, 0);
            acc[mt][1] = __builtin_amdgcn_mfma_f32_16x16x32_bf16(ah, bh1, acc[mt][1], 0, 0, 0);
            acc[mt][1] = __builtin_amdgcn_mfma_f32_16x16x32_bf16(ah, bl1, acc[mt][1], 0, 0, 0);
        }
        bh0 = nh0; bl0 = nl0; bh1 = nh1; bl1 = nl1;
    }
}

extern "C" __global__ void __launch_bounds__(THREADS, 4)
fused_stress(const float* __restrict__ emb,
             const float* __restrict__ b1,
             const float* __restrict__ b2,
             const float* __restrict__ W3, const float* __restrict__ b3,
             const float* __restrict__ wl2, const int* __restrict__ natoms,
             float* __restrict__ out, int NPG) {
    __shared__ u16 sX[XROWS * 128];     // 28 KB, single bf16 plane
    __shared__ float s_acc[6];          // [0]=iso sum, [1..5]=aniso sums

    const int tid = threadIdx.x;
    const int l   = tid & 63;
    const int w   = tid >> 6;           // wave 0..3
    const int lr  = l & 15;
    const int lkg = l >> 4;             // 0..3
    const int g   = blockIdx.x;
    const size_t nodebase = (size_t)g * (size_t)NPG;

    if (tid < 6) s_acc[tid] = 0.0f;
    __syncthreads();

    // ---- single-pass stream: per node read x0 row + aniso rows 4..8 together ----
    // Each 32-lane group handles nodes h, h+8, h+16, ... (8 groups -> 8
    // consecutive nodes in flight). x0 -> bf16 -> sX (swizzled); rows 4..8 ->
    // dot with w_l2 -> lane-local accumulators. One DRAM-page walk per region.
    {
        const int h = tid >> 5;          // 32-lane group 0..7
        const int c = tid & 31;
        const f32x4 wv = ((const f32x4*)wl2)[c];
        float a0 = 0.f, a1 = 0.f, a2 = 0.f, a3 = 0.f, a4 = 0.f;
        #pragma unroll 2
        for (int i = 0; i < 14; ++i) {
            const int node = h + 8 * i;
            const int ksw = (c * 4) ^ ((node & 7) << 3);
            if (node < NPG) {
                const f32x4* nb4 = (const f32x4*)(emb + (nodebase + node) * (9 * C_DIM));
                f32x4 x0v = __builtin_nontemporal_load(nb4 + c);
                f32x4 v0  = __builtin_nontemporal_load(nb4 + 128 + c);
                f32x4 v1  = __builtin_nontemporal_load(nb4 + 160 + c);
                f32x4 v2  = __builtin_nontemporal_load(nb4 + 192 + c);
                f32x4 v3  = __builtin_nontemporal_load(nb4 + 224 + c);
                f32x4 v4  = __builtin_nontemporal_load(nb4 + 256 + c);
                u32 p01 = (u32)bf16_rn(x0v[0]) | ((u32)bf16_rn(x0v[1]) << 16);
                u32 p23 = (u32)bf16_rn(x0v[2]) | ((u32)bf16_rn(x0v[3]) << 16);
                *(uint2*)(&sX[node * 128 + ksw]) = make_uint2(p01, p23);
                a0 += dot4v(v0, wv);
                a1 += dot4v(v1, wv);
                a2 += dot4v(v2, wv);
                a3 += dot4v(v3, wv);
                a4 += dot4v(v4, wv);
            } else if (node < XROWS) {
                *(uint2*)(&sX[node * 128 + ksw]) = make_uint2(0u, 0u);
            }
        }
        #pragma unroll
        for (int s = 1; s < 32; s <<= 1) {
            a0 += __shfl_xor(a0, s);
            a1 += __shfl_xor(a1, s);
            a2 += __shfl_xor(a2, s);
            a3 += __shfl_xor(a3, s);
            a4 += __shfl_xor(a4, s);
        }
        if (c == 0) {
            atomicAdd(&s_acc[1], a0);
            atomicAdd(&s_acc[2], a1);
            atomicAdd(&s_acc[3], a2);
            atomicAdd(&s_acc[4], a3);
            atomicAdd(&s_acc[5], a4);
        }
    }
    __syncthreads();

    f32x4 acc[MT][2];
    const int nt0 = w * 2;

    // ---- layer 1: h = silu(x0 @ W1^T + b1) ----
    gemm_layer_pk(&g_wpack[0][0][0][0][0][0], sX, nt0, l, acc);
    __syncthreads();   // everyone done reading sX (x0)

    // write h back into sX (bf16, swizzled)
    {
        #pragma unroll
        for (int t = 0; t < 2; ++t) {
            const int j = (nt0 + t) * 16 + lr;
            const float bj = b1[j];
            #pragma unroll
            for (int mt = 0; mt < MT; ++mt) {
                #pragma unroll
                for (int r = 0; r < 4; ++r) {
                    const int row = mt * 16 + lkg * 4 + r;
                    const float hv = silu_f(acc[mt][t][r] + bj);
                    sX[row * 128 + (j ^ ((row & 7) << 3))] = bf16_rn(hv);
                }
            }
        }
    }
    __syncthreads();

    // ---- layer 2: h2 = silu(h @ W2^T + b2); s = h2 . W3 ; block-sum ----
    gemm_layer_pk(&g_wpack[1][0][0][0][0][0], sX, nt0, l, acc);
    {
        float w3j[2], b2j[2];
        #pragma unroll
        for (int t = 0; t < 2; ++t) {
            const int j = (nt0 + t) * 16 + lr;
            w3j[t] = W3[j];
            b2j[t] = b2[j];
        }
        float psum = 0.0f;
        #pragma unroll
        for (int mt = 0; mt < MT; ++mt) {
            #pragma unroll
            for (int r = 0; r < 4; ++r) {
                const int row = mt * 16 + lkg * 4 + r;
                if (row < NPG) {
                    psum += silu_f(acc[mt][0][r] + b2j[0]) * w3j[0]
                          + silu_f(acc[mt][1][r] + b2j[1]) * w3j[1];
                }
            }
        }
        // full-wave reduce (sums over lr and lkg; all lanes same graph)
        #pragma unroll
        for (int s = 1; s < 64; s <<= 1)
            psum += __shfl_xor(psum, s);
        if (l == 0)
            atomicAdd(&s_acc[0], psum);
    }
    __syncthreads();

    // ---- finalize: dec = [iso, 0,0,0, aniso]; out = dec @ CG ----
    if (tid < 9) {
        const float inv = 1.0f / (float)natoms[g];
        const float iso = (s_acc[0] + (float)NPG * b3[0]) * inv;
        float o = iso * CG_TAB[0][tid];
        #pragma unroll
        for (int m = 0; m < 5; ++m)
            o += (s_acc[1 + m] * inv) * CG_TAB[1 + m][tid];
        out[(size_t)g * 9 + tid] = o;
    }
}

extern "C" void kernel_launch(void* const* d_in, const int* in_sizes, int n_in,
                              void* d_out, int out_size, void* d_ws, size_t ws_size,
                              hipStream_t stream) {
    const float* emb    = (const float*)d_in[0];
    const float* W1     = (const float*)d_in[1];
    const float* b1     = (const float*)d_in[2];
    const float* W2     = (const float*)d_in[3];
    const float* b2     = (const float*)d_in[4];
    const float* W3     = (const float*)d_in[5];
    const float* b3     = (const float*)d_in[6];
    const float* wl2    = (const float*)d_in[7];
    const int*   natoms = (const int*)d_in[9];

    const int G   = in_sizes[9];
    const int N   = in_sizes[0] / (9 * C_DIM);
    const int NPG = N / G;   // 100 for this problem; kernel supports NPG <= 112

    prep_wpack<<<8, 512, 0, stream>>>(W1, W2);
    fused_stress<<<G, THREADS, 0, stream>>>(emb, b1, b2, W3, b3, wl2,
                                            natoms, (float*)d_out, NPG);
}